// Round 8
// baseline (77.366 us; speedup 1.0000x reference)
//
#include <hip/hip_runtime.h>
#include <math.h>

#define S_LEN 2048
#define B_SZ  2
#define H_DIM 512
#define WIN   128
#define PAD   64
#define SP    (S_LEN + WIN)   /* 2176 padded seq length */
#define SCALE 0.044194173824159216f  /* 1/sqrt(512) */
#define TQ    32

typedef __bf16 bf16;
typedef __attribute__((ext_vector_type(8))) __bf16 bf16x8;
typedef __attribute__((ext_vector_type(4))) __bf16 bf16x4;
typedef __attribute__((ext_vector_type(4))) float f32x4;

#define GLDS16(g, l) __builtin_amdgcn_global_load_lds( \
    (const __attribute__((address_space(1))) void*)(g), \
    (__attribute__((address_space(3))) void*)(l), 16, 0, 0)

// ---------------- fused prep ---------------------------------------------
// R0: [0,262144)        x -> xb bf16 (8/thread)
// R1: [262144,524288)   Wq,Wk -> whi/wlo rows 0-1023 ; Wo -> rows 1536-2047 ;
//                       Wv -> wvThi/wvTlo (scatter-transpose)
// R2: [524288,557056)   zero pads of pKb (rows) and pUT (cols)
// R3: [557056,819200)   rope tables (exp2f/sinf, f32)
// R4: [819200,821248)   bvoV = Wo.bv (4 lanes per output; bo added in attn)
__global__ __launch_bounds__(256) void prep_k(
    const float* __restrict__ x,
    const float* __restrict__ Wq, const float* __restrict__ Wk,
    const float* __restrict__ Wv, const float* __restrict__ Wo,
    const float* __restrict__ bv,
    bf16* __restrict__ xb, bf16* __restrict__ whi, bf16* __restrict__ wlo,
    bf16* __restrict__ wvThi, bf16* __restrict__ wvTlo,
    bf16* __restrict__ pKb, bf16* __restrict__ pUT,
    float* __restrict__ sinT, float* __restrict__ cosT,
    float* __restrict__ bvoV)
{
  int i = blockIdx.x * 256 + threadIdx.x;
  if (i < 262144) {                     // R0
    int e = i * 8;
    float4 v0 = *(const float4*)(x + e);
    float4 v1 = *(const float4*)(x + e + 4);
    bf16x8 o = {(bf16)v0.x, (bf16)v0.y, (bf16)v0.z, (bf16)v0.w,
                (bf16)v1.x, (bf16)v1.y, (bf16)v1.z, (bf16)v1.w};
    *(bf16x8*)(xb + e) = o;
  } else if (i < 524288) {              // R1
    int idx = (i - 262144) * 4;
    int m = idx >> 18;
    const float* src = (m == 0) ? Wq : (m == 1) ? Wk : (m == 2) ? Wv : Wo;
    float4 v = *(const float4*)(src + (idx & 262143));
    bf16 h0 = (bf16)v.x, h1 = (bf16)v.y, h2 = (bf16)v.z, h3 = (bf16)v.w;
    bf16 l0 = (bf16)(v.x - (float)h0), l1 = (bf16)(v.y - (float)h1);
    bf16 l2 = (bf16)(v.z - (float)h2), l3 = (bf16)(v.w - (float)h3);
    if (m == 2) {                       // Wv: scatter-transpose (wvT[h][k]=Wv[k][h])
      int r  = (idx & 262143) >> 9;     // Wv row (k)
      int hc = idx & 511;               // first of 4 h-cols
      wvThi[(size_t)(hc + 0) * 512 + r] = h0; wvTlo[(size_t)(hc + 0) * 512 + r] = l0;
      wvThi[(size_t)(hc + 1) * 512 + r] = h1; wvTlo[(size_t)(hc + 1) * 512 + r] = l1;
      wvThi[(size_t)(hc + 2) * 512 + r] = h2; wvTlo[(size_t)(hc + 2) * 512 + r] = l2;
      wvThi[(size_t)(hc + 3) * 512 + r] = h3; wvTlo[(size_t)(hc + 3) * 512 + r] = l3;
    } else {                            // Wq,Wk rows 0-1023; Wo rows 1536-2047
      bf16x4 hv = {h0, h1, h2, h3};
      bf16x4 lv = {l0, l1, l2, l3};
      *(bf16x4*)(whi + idx) = hv;
      *(bf16x4*)(wlo + idx) = lv;
    }
  } else if (i < 557056) {              // R2: pads
    int idx = i - 524288;
    float4 z = {0.f, 0.f, 0.f, 0.f};
    if (idx < 16384) {        // pKb: 2b x 128 pad-rows x 512 cols
      int b = idx >> 13, r = (idx & 8191) >> 6, c = idx & 63;
      int row = (r < 64) ? r : (S_LEN + r);
      *(float4*)(pKb + ((size_t)b * SP + row) * 512 + c * 8) = z;
    } else {                  // pUT: 2b x 512 rows x 128 pad-cols
      int j = idx - 16384;
      int b = j >> 13, h = (j & 8191) >> 4, v = j & 15;
      int col = (v < 8) ? v * 8 : (S_LEN + PAD + (v - 8) * 8);
      *(float4*)(pUT + ((size_t)b * 512 + h) * SP + col) = z;
    }
  } else if (i < 819200) {              // R3: rope tables
    int idx = i - 557056;               // s*128 + jj
    int s = idx >> 7, jj = idx & 127;
    float fqA = exp2f(-(float)jj * 0.10381025296523f);
    float fqB = exp2f(-(float)(2 * jj + 1) * 0.05190512648262f);
    float aA = (float)s * fqA;
    float aB = (float)s * fqB;
    sinT[s * 256 + jj]       = sinf(aA);
    sinT[s * 256 + jj + 128] = cosf(aA);
    cosT[s * 256 + jj]       = sinf(aB);
    cosT[s * 256 + jj + 128] = cosf(aB);
  } else {                              // R4: bvoV = Wo.bv
    int t = i - 819200;                 // [0,2048)
    int j = t >> 2, q = t & 3;
    const float* wr = Wo + (size_t)j * 512 + q * 128;
    float s = 0.f;
#pragma unroll
    for (int k2 = 0; k2 < 32; k2++) {
      float4 w4 = *(const float4*)(wr + k2 * 4);
      float4 b4 = *(const float4*)(bv + q * 128 + k2 * 4);
      s += w4.x * b4.x + w4.y * b4.y + w4.z * b4.z + w4.w * b4.w;
    }
    s += __shfl_xor(s, 1);
    s += __shfl_xor(s, 2);
    if (q == 0) bvoV[j] = s;
  }
}

// ---------------- W2 = Wo @ Wv (3-pass split-bf16, 16 blocks) ------------
// A = whi/wlo rows 1536-2047 (Wo), B = wvT hi/lo (Wv columns).
// Epilogue: hi/lo split into whi/wlo rows 1024-1535 (the U weight region).
__global__ __launch_bounds__(256) void w2_k(
    const bf16* __restrict__ whiR, const bf16* __restrict__ wloR,
    const bf16* __restrict__ wvThi, const bf16* __restrict__ wvTlo,
    bf16* __restrict__ whiW, bf16* __restrict__ wloW)
{
  __shared__ __align__(16) unsigned char smem[2 * 32768];
  const int tid = threadIdx.x, lane = tid & 63, wid = tid >> 6;
  const int wm = wid >> 1, wn = wid & 1;
  const int lr = lane & 15, lk = lane >> 4;
  const int j0 = blockIdx.x * 128, h0 = blockIdx.y * 128;
  f32x4 acc[4][4] = {};

  auto stage = [&](int k0, int sel) {
    unsigned char* buf = smem + sel * 32768;
#pragma unroll
    for (int it = 0; it < 4; it++) {
      int c = tid + it * 256;
      int r = c >> 3, p = c & 7, l = p ^ (r & 7);
      GLDS16(((l < 4) ? whiR : wloR) + (size_t)(1536 + j0 + r) * 512 + k0 + (l & 3) * 8,
             buf + c * 16);
    }
#pragma unroll
    for (int it = 0; it < 4; it++) {
      int c = tid + it * 256;
      int r = c >> 3, p = c & 7, l = p ^ (r & 7);
      GLDS16(((l < 4) ? wvThi : wvTlo) + (size_t)(h0 + r) * 512 + k0 + (l & 3) * 8,
             buf + 16384 + c * 16);
    }
  };

  stage(0, 0);
  __syncthreads();
  for (int t = 0; t < 16; t++) {
    if (t < 15) stage((t + 1) * 32, (t + 1) & 1);
    const unsigned char* buf = smem + (t & 1) * 32768;
    bf16x8 ah[4], al[4], bh[4], bl[4];
#pragma unroll
    for (int mi = 0; mi < 4; mi++) {
      int r = wm * 64 + mi * 16 + lr;
      const unsigned char* base = buf + r * 128;
      int sw = (r & 7) << 4;
      ah[mi] = *(const bf16x8*)(base + ((lk * 16) ^ sw));
      al[mi] = *(const bf16x8*)(base + ((64 + lk * 16) ^ sw));
    }
#pragma unroll
    for (int ni = 0; ni < 4; ni++) {
      int r = wn * 64 + ni * 16 + lr;
      const unsigned char* base = buf + 16384 + r * 128;
      int sw = (r & 7) << 4;
      bh[ni] = *(const bf16x8*)(base + ((lk * 16) ^ sw));
      bl[ni] = *(const bf16x8*)(base + ((64 + lk * 16) ^ sw));
    }
#pragma unroll
    for (int mi = 0; mi < 4; mi++)
#pragma unroll
      for (int ni = 0; ni < 4; ni++) {
        acc[mi][ni] = __builtin_amdgcn_mfma_f32_16x16x32_bf16(ah[mi], bh[ni], acc[mi][ni], 0, 0, 0);
        acc[mi][ni] = __builtin_amdgcn_mfma_f32_16x16x32_bf16(ah[mi], bl[ni], acc[mi][ni], 0, 0, 0);
        acc[mi][ni] = __builtin_amdgcn_mfma_f32_16x16x32_bf16(al[mi], bh[ni], acc[mi][ni], 0, 0, 0);
      }
    __syncthreads();
  }
#pragma unroll
  for (int mi = 0; mi < 4; mi++)
#pragma unroll
    for (int ni = 0; ni < 4; ni++) {
      int col = h0 + wn * 64 + ni * 16 + lr;
#pragma unroll
      for (int g = 0; g < 4; g++) {
        int row = j0 + wm * 64 + mi * 16 + lk * 4 + g;
        float v = acc[mi][ni][g];
        bf16 h = (bf16)v;
        whiW[(size_t)(1024 + row) * 512 + col] = h;
        wloW[(size_t)(1024 + row) * 512 + col] = (bf16)(v - (float)h);
      }
    }
}

// ---------------- 2-pass split-bf16 QKVU GEMM ----------------------------
// C = xb @ Wcat^T, regions (blockIdx.y>>2): 0=Q (rope+bias), 1=K
// (rope+bias+pad), 2=U=x@W2^T (no bias, transpose+pad -> pUT).
__global__ __launch_bounds__(256) void qkvu_k(
    const bf16* __restrict__ Ab,
    const bf16* __restrict__ Whi, const bf16* __restrict__ Wlo,
    const float* __restrict__ bq, const float* __restrict__ bk,
    const float* __restrict__ sinT, const float* __restrict__ cosT,
    bf16* __restrict__ oQ, bf16* __restrict__ oK, bf16* __restrict__ oUT)
{
  constexpr int BM = 128;
  constexpr int ABYTES = BM * 64;
  constexpr int BUFB = ABYTES + 128 * 128;
  __shared__ __align__(16) unsigned char smem[2 * BUFB];
  const int tid = threadIdx.x;
  const int lane = tid & 63, wid = tid >> 6;
  const int wm = wid >> 1, wn = wid & 1;
  const int row0 = blockIdx.x * BM;
  const int wrow0 = blockIdx.y * 128;
  const int lr = lane & 15, lk = lane >> 4;

  f32x4 acc[4][4] = {};

  auto stage = [&](int k0, int bufsel) {
    unsigned char* buf = smem + bufsel * BUFB;
#pragma unroll
    for (int i = 0; i < 2; i++) {           // A: 128 rows x 4 slots (bf16)
      int c = tid + i * 256;
      int r = c >> 2, p = c & 3, l = p ^ (r & 3);
      GLDS16(Ab + (size_t)(row0 + r) * 512 + k0 + l * 8, buf + c * 16);
    }
#pragma unroll
    for (int j = 0; j < 4; j++) {           // B: 128 rows x 8 slots [hi|lo]
      int c = tid + j * 256;
      int r = c >> 3, p = c & 7, l = p ^ (r & 7);
      const bf16* src = ((l < 4) ? Whi : Wlo) + (size_t)(wrow0 + r) * 512 + k0 + (l & 3) * 8;
      GLDS16(src, buf + ABYTES + c * 16);
    }
  };

  stage(0, 0);
  __syncthreads();
  for (int t = 0; t < 16; t++) {
    if (t < 15) stage((t + 1) * 32, (t + 1) & 1);
    const unsigned char* buf = smem + (t & 1) * BUFB;
    bf16x8 bfr[4][2];
#pragma unroll
    for (int ni = 0; ni < 4; ni++) {
      int r = wn * 64 + ni * 16 + lr;
      const unsigned char* base = buf + ABYTES + r * 128;
      int sw = (r & 7) << 4;
      bfr[ni][0] = *(const bf16x8*)(base + ((lk * 16) ^ sw));
      bfr[ni][1] = *(const bf16x8*)(base + ((64 + lk * 16) ^ sw));
    }
    bf16x8 ah[4];
#pragma unroll
    for (int mi = 0; mi < 4; mi++) {
      int r = wm * 64 + mi * 16 + lr;
      ah[mi] = *(const bf16x8*)(buf + r * 64 + ((lk * 16) ^ ((r & 3) << 4)));
    }
#pragma unroll
    for (int mi = 0; mi < 4; mi++)
#pragma unroll
      for (int ni = 0; ni < 4; ni++) {
        acc[mi][ni] = __builtin_amdgcn_mfma_f32_16x16x32_bf16(ah[mi], bfr[ni][0], acc[mi][ni], 0, 0, 0);
        acc[mi][ni] = __builtin_amdgcn_mfma_f32_16x16x32_bf16(ah[mi], bfr[ni][1], acc[mi][ni], 0, 0, 0);
      }
    __syncthreads();
  }

  const int rowb = row0 + wm * 64 + ((lane >> 4) * 4);
  const int region = blockIdx.y >> 2;                 // 0=Q 1=K 2=U
  const int cm0 = (blockIdx.y & 3) * 128;
#pragma unroll
  for (int mi = 0; mi < 4; mi++)
#pragma unroll
    for (int ni = 0; ni < 4; ni++) {
      int c = cm0 + wn * 64 + ni * 16 + (lane & 15);
      if (region == 2) {
#pragma unroll
        for (int g = 0; g < 4; g++) {
          int rr = rowb + mi * 16 + g;
          int b = rr >> 11, s = rr & 2047;
          oUT[((size_t)b * 512 + c) * SP + PAD + s] = (bf16)acc[mi][ni][g];
        }
      } else {
        const float* bias = (region == 0) ? bq : bk;
        float bb = bias[c];
        int j = c >> 1, par = c & 1;
#pragma unroll
        for (int g = 0; g < 4; g++) {
          int rr = rowb + mi * 16 + g;
          int s = rr & 2047;
          float v = acc[mi][ni][g] + bb;
          float p = __shfl_xor(v, 1);
          float es = sinT[s * 256 + j], ec = cosT[s * 256 + j];
          float res = par ? (p * es + v * ec) : (v * ec - p * es);
          int oc = par ? (j + 256) : j;
          if (region == 0) oQ[(size_t)rr * 512 + oc] = (bf16)res;
          else { int b = rr >> 11; oK[((size_t)b * SP + PAD + s) * 512 + oc] = (bf16)res; }
        }
      }
    }
}

// ---------------- banded MFMA attention + fused O-proj -------------------
// grid (128, 2): block = 32 queries x 256 output h-cols (y half).
// Phase 1: S = Q K^T ; Phase 2: banded softmax -> P bf16, plus
//   sfrac[row] = 1 - (pad-key probability mass)  [round-6 bug fix]
// Phase 3: out = P U + sfrac*bvoV + bo  (f32 direct to d_out)
__global__ __launch_bounds__(256) void attn_mfma_k(
    const bf16* __restrict__ rQb, const bf16* __restrict__ pKb,
    const bf16* __restrict__ pUT, const float* __restrict__ bvoV,
    const float* __restrict__ bo, float* __restrict__ out)
{
  __shared__ __align__(16) unsigned char smem[53888];
  const int tid = threadIdx.x, lane = tid & 63, w = tid >> 6;
  const int q0g = blockIdx.x * TQ;
  const int nbase = blockIdx.y * 256;
  const int b = q0g >> 11, s0 = q0g & 2047;
  const int lr = lane & 15, lk = lane >> 4;
  const int OFF_K = 4096, OFF_P = 43008, OFF_SF = 53760;

  // ---- phase 1: scores
  f32x4 sacc[5] = {};
  const int tm = w >> 1, tnb = (w & 1) * 5;
  for (int k0 = 0; k0 < 512; k0 += 64) {
    __syncthreads();
    {
      int r = tid >> 3, p = tid & 7, l = p ^ (r & 7);
      GLDS16(rQb + (size_t)(q0g + r) * 512 + k0 + l * 8, smem + (w * 64) * 16);
    }
#pragma unroll
    for (int i = 0; i < 5; i++) {
      int c = tid + i * 256;
      int r = c >> 3, p = c & 7, l = p ^ (r & 7);
      GLDS16(pKb + ((size_t)b * SP + s0 + r) * 512 + k0 + l * 8,
             smem + OFF_K + (i * 256 + w * 64) * 16);
    }
    __syncthreads();
    __builtin_amdgcn_s_setprio(1);
#pragma unroll
    for (int kk = 0; kk < 2; kk++) {
      int arow = tm * 16 + lr;
      bf16x8 a = *(const bf16x8*)(smem + arow * 128 + (((kk * 64 + lk * 16) ^ ((arow & 7) << 4))));
#pragma unroll
      for (int i = 0; i < 5; i++) {
        int brow = (tnb + i) * 16 + lr;
        bf16x8 bb = *(const bf16x8*)(smem + OFF_K + brow * 128 + (((kk * 64 + lk * 16) ^ ((brow & 7) << 4))));
        sacc[i] = __builtin_amdgcn_mfma_f32_16x16x32_bf16(a, bb, sacc[i], 0, 0, 0);
      }
    }
    __builtin_amdgcn_s_setprio(0);
  }
  __syncthreads();
  {   // write scores f32 [32][164]
    float* sc = (float*)smem;
#pragma unroll
    for (int i = 0; i < 5; i++) {
      int col = (tnb + i) * 16 + lr;
#pragma unroll
      for (int g = 0; g < 4; g++) {
        int row = tm * 16 + lk * 4 + g;
        sc[row * 164 + col] = sacc[i][g] * SCALE;
      }
    }
  }
  __syncthreads();
  // ---- phase 2: banded softmax + sfrac, 8 threads per row
  {
    float* sc = (float*)smem;
    bf16* P = (bf16*)(smem + OFF_P);
    float* sf = (float*)(smem + OFF_SF);
    int row = tid >> 3, j0 = tid & 7;
    float vals[20];
    float mx = -1e30f;
#pragma unroll
    for (int i = 0; i < 20; i++) {
      int j = j0 + i * 8;
      bool valid = (j >= row) && (j <= row + 127);
      float v = valid ? sc[row * 164 + j] : -1e30f;
      vals[i] = v;
      mx = fmaxf(mx, v);
    }
#pragma unroll
    for (int off = 1; off < 8; off <<= 1) mx = fmaxf(mx, __shfl_xor(mx, off));
    float sum = 0.f, epad = 0.f;
#pragma unroll
    for (int i = 0; i < 20; i++) {
      int j = j0 + i * 8;
      float e = (vals[i] > -1e29f) ? __expf(vals[i] - mx) : 0.f;
      vals[i] = e; sum += e;
      // pad key iff global padded index s0+j is outside [PAD, PAD+S_LEN)
      if ((unsigned)(s0 + j - PAD) >= (unsigned)S_LEN) epad += e;
    }
#pragma unroll
    for (int off = 1; off < 8; off <<= 1) {
      sum += __shfl_xor(sum, off);
      epad += __shfl_xor(epad, off);
    }
    float inv = 1.f / sum;
    if (j0 == 0) sf[row] = 1.f - epad * inv;
#pragma unroll
    for (int i = 0; i < 20; i++) {
      int j = j0 + i * 8;
      P[row * 168 + j] = (bf16)(vals[i] * inv);   // row stride 336B
    }
  }
  // ---- phase 3: out = P @ U + sfrac*bvoV + bo (this block's 256-col half)
  const bf16* pUTb = pUT + (size_t)b * 512 * SP;
  const float* sfp = (const float*)(smem + OFF_SF);
  const int utm = w >> 1, utnb = (w & 1) * 4;
  for (int n0 = nbase; n0 < nbase + 256; n0 += 128) {
    __syncthreads();
    {   // stage U chunk: 128 h-rows x 160 keys, LDS row stride 336B
      int r = tid >> 1, half = tid & 1;
      const bf16* src = pUTb + (size_t)(n0 + r) * SP + s0;
#pragma unroll
      for (int i = 0; i < 10; i++) {
        int slot = half * 10 + i;
        float4 v = *(const float4*)(src + slot * 8);
        *(float4*)(smem + r * 336 + slot * 16) = v;
      }
    }
    __syncthreads();
    f32x4 oacc[4] = {};
    __builtin_amdgcn_s_setprio(1);
#pragma unroll
    for (int tk = 0; tk < 5; tk++) {
      int arow = utm * 16 + lr;
      bf16x8 a = *(const bf16x8*)(smem + OFF_P + arow * 336 + tk * 64 + lk * 16);
#pragma unroll
      for (int i = 0; i < 4; i++) {
        int brow = (utnb + i) * 16 + lr;
        bf16x8 bb = *(const bf16x8*)(smem + brow * 336 + tk * 64 + lk * 16);
        oacc[i] = __builtin_amdgcn_mfma_f32_16x16x32_bf16(a, bb, oacc[i], 0, 0, 0);
      }
    }
    __builtin_amdgcn_s_setprio(0);
    float sfv[4];
#pragma unroll
    for (int g = 0; g < 4; g++) sfv[g] = sfp[utm * 16 + lk * 4 + g];
#pragma unroll
    for (int i = 0; i < 4; i++) {
      int col = n0 + (utnb + i) * 16 + lr;
      float bV = bvoV[col], bO = bo[col];
#pragma unroll
      for (int g = 0; g < 4; g++) {
        int row = utm * 16 + lk * 4 + g;
        out[(size_t)(q0g + row) * 512 + col] = oacc[i][g] + sfv[g] * bV + bO;
      }
    }
  }
}

// ---------------- launch -------------------------------------------------
extern "C" void kernel_launch(void* const* d_in, const int* in_sizes, int n_in,
                              void* d_out, int out_size, void* d_ws, size_t ws_size,
                              hipStream_t stream) {
  const float* x  = (const float*)d_in[0];
  const float* Wq = (const float*)d_in[1];
  const float* bq = (const float*)d_in[2];
  const float* Wk = (const float*)d_in[3];
  const float* bk = (const float*)d_in[4];
  const float* Wv = (const float*)d_in[5];
  const float* bv = (const float*)d_in[6];
  const float* Wo = (const float*)d_in[7];
  const float* bo = (const float*)d_in[8];
  float* out = (float*)d_out;

  const size_t NQ = (size_t)B_SZ * S_LEN * H_DIM;  // 2,097,152
  const size_t NP = (size_t)B_SZ * SP * H_DIM;     // 2,228,224
  float* sinT = (float*)d_ws;                      // 524288 f32
  float* cosT = sinT + (size_t)S_LEN * 256;        // 524288 f32
  float* bvoV = cosT + (size_t)S_LEN * 256;        // 512 f32
  bf16* xb    = (bf16*)(bvoV + 512);               // NQ
  bf16* whi   = xb + NQ;                           // 2048*512
  bf16* wlo   = whi + 2048 * 512;                  // 2048*512
  bf16* wvThi = wlo + 2048 * 512;                  // 512*512
  bf16* wvTlo = wvThi + 512 * 512;                 // 512*512
  bf16* rQb   = wvTlo + 512 * 512;                 // NQ
  bf16* pKb   = rQb + NQ;                          // NP
  bf16* pUT   = pKb + NP;                          // NP
  // total ~30 MB

  prep_k<<<3208, 256, 0, stream>>>(x, Wq, Wk, Wv, Wo, bv,
      xb, whi, wlo, wvThi, wvTlo, pKb, pUT, sinT, cosT, bvoV);

  w2_k<<<dim3(4, 4), 256, 0, stream>>>(whi, wlo, wvThi, wvTlo, whi, wlo);

  qkvu_k<<<dim3(32, 12), 256, 0, stream>>>(xb, whi, wlo,
      bq, bk, sinT, cosT, rQb, pKb, pUT);

  attn_mfma_k<<<dim3(B_SZ * S_LEN / TQ, 2), 256, 0, stream>>>(
      rQb, pKb, pUT, bvoV, bo, out);
}

// Round 9
// 61.571 us; speedup vs baseline: 1.2565x; 1.2565x over previous
//
#include <hip/hip_runtime.h>
#include <math.h>

#define S_LEN 2048
#define B_SZ  2
#define H_DIM 512
#define WIN   128
#define PAD   64
#define SP    (S_LEN + WIN)   /* 2176 padded seq length */
#define SCALE 0.044194173824159216f  /* 1/sqrt(512) */
#define TQA   16               /* attn queries per block */

typedef __bf16 bf16;
typedef __attribute__((ext_vector_type(8))) __bf16 bf16x8;
typedef __attribute__((ext_vector_type(4))) __bf16 bf16x4;
typedef __attribute__((ext_vector_type(4))) float f32x4;

#define GLDS16(g, l) __builtin_amdgcn_global_load_lds( \
    (const __attribute__((address_space(1))) void*)(g), \
    (__attribute__((address_space(3))) void*)(l), 16, 0, 0)

// ---------------- fused prep: x->bf16 | W->hi/lo | pads | rope tables ----
// R0: [0,262144)       x -> xb (8 elems/thread)
// R1: [262144,524288)  Wq|Wk|Wv|Wo -> whi/wlo (4 elems/thread)
// R2: [524288,557056)  zero pads of pKb (row-pad) and pVT (col-pad)
// R3: [557056,819200)  rope tables via exp2f/sinf (f32)
__global__ __launch_bounds__(256) void prep_k(
    const float* __restrict__ x,
    const float* __restrict__ Wq, const float* __restrict__ Wk,
    const float* __restrict__ Wv, const float* __restrict__ Wo,
    bf16* __restrict__ xb, bf16* __restrict__ whi, bf16* __restrict__ wlo,
    bf16* __restrict__ pKb, bf16* __restrict__ pVT,
    float* __restrict__ sinT, float* __restrict__ cosT)
{
  int i = blockIdx.x * 256 + threadIdx.x;
  if (i < 262144) {                     // R0: x -> bf16
    int e = i * 8;
    float4 v0 = *(const float4*)(x + e);
    float4 v1 = *(const float4*)(x + e + 4);
    bf16x8 o = {(bf16)v0.x, (bf16)v0.y, (bf16)v0.z, (bf16)v0.w,
                (bf16)v1.x, (bf16)v1.y, (bf16)v1.z, (bf16)v1.w};
    *(bf16x8*)(xb + e) = o;
  } else if (i < 524288) {              // R1: weights hi/lo
    int idx = (i - 262144) * 4;
    int m = idx >> 18;
    const float* src = (m == 0) ? Wq : (m == 1) ? Wk : (m == 2) ? Wv : Wo;
    float4 v = *(const float4*)(src + (idx & 262143));
    bf16 h0 = (bf16)v.x, h1 = (bf16)v.y, h2 = (bf16)v.z, h3 = (bf16)v.w;
    bf16x4 hv = {h0, h1, h2, h3};
    bf16x4 lv = {(bf16)(v.x - (float)h0), (bf16)(v.y - (float)h1),
                 (bf16)(v.z - (float)h2), (bf16)(v.w - (float)h3)};
    *(bf16x4*)(whi + idx) = hv;
    *(bf16x4*)(wlo + idx) = lv;
  } else if (i < 557056) {              // R2: pads
    int idx = i - 524288;
    float4 z = {0.f, 0.f, 0.f, 0.f};
    if (idx < 16384) {        // pKb: 2b x 128 pad-rows x 512 cols
      int b = idx >> 13, r = (idx & 8191) >> 6, c = idx & 63;
      int row = (r < 64) ? r : (S_LEN + r);
      *(float4*)(pKb + ((size_t)b * SP + row) * 512 + c * 8) = z;
    } else {                  // pVT: 2b x 512 rows x 128 pad-cols
      int j = idx - 16384;
      int b = j >> 13, h = (j & 8191) >> 4, v = j & 15;
      int col = (v < 8) ? v * 8 : (S_LEN + PAD + (v - 8) * 8);
      *(float4*)(pVT + ((size_t)b * 512 + h) * SP + col) = z;
    }
  } else {                              // R3: rope tables
    int idx = i - 557056;               // [0, 262144) = s*128 + jj
    int s = idx >> 7, jj = idx & 127;
    float fqA = exp2f(-(float)jj * 0.10381025296523f);          // i = 2jj
    float fqB = exp2f(-(float)(2 * jj + 1) * 0.05190512648262f); // i = 2jj+1
    float aA = (float)s * fqA;
    float aB = (float)s * fqB;
    sinT[s * 256 + jj]       = sinf(aA);
    sinT[s * 256 + jj + 128] = cosf(aA);
    cosT[s * 256 + jj]       = sinf(aB);
    cosT[s * 256 + jj + 128] = cosf(aB);
  }
}

// ---------------- 2-pass split-bf16 MFMA GEMM (round-7 verified) --------
template<int MFR, int MODE>
__global__ __launch_bounds__(256) void gemm_k(
    const bf16* __restrict__ Ab,
    const bf16* __restrict__ Whi, const bf16* __restrict__ Wlo,
    const float* __restrict__ bq, const float* __restrict__ bk,
    const float* __restrict__ bv,
    const float* __restrict__ sinT, const float* __restrict__ cosT,
    bf16* __restrict__ oQ, bf16* __restrict__ oK, bf16* __restrict__ oVT,
    float* __restrict__ oOut)
{
  constexpr int BM = MFR * 32;
  constexpr int ABYTES = BM * 64;
  constexpr int BUFB = ABYTES + 128 * 128;
  __shared__ __align__(16) unsigned char smem[2 * BUFB];
  const int tid = threadIdx.x;
  const int lane = tid & 63, wid = tid >> 6;
  const int wm = wid >> 1, wn = wid & 1;
  const int row0 = blockIdx.x * BM;
  const int wrow0 = (MODE == 0 ? 0 : 1536) + blockIdx.y * 128;
  const int lr = lane & 15, lk = lane >> 4;

  f32x4 acc[MFR][4] = {};

  auto stage = [&](int k0, int bufsel) {
    unsigned char* buf = smem + bufsel * BUFB;
#pragma unroll
    for (int i = 0; i < MFR / 2; i++) {     // A: BM rows x 4 slots
      int c = tid + i * 256;
      int r = c >> 2, p = c & 3, l = p ^ (r & 3);
      GLDS16(Ab + (size_t)(row0 + r) * 512 + k0 + l * 8, buf + c * 16);
    }
#pragma unroll
    for (int j = 0; j < 4; j++) {           // B: 128 rows x 8 slots [hi|lo]
      int c = tid + j * 256;
      int r = c >> 3, p = c & 7, l = p ^ (r & 7);
      const bf16* src = ((l < 4) ? Whi : Wlo) + (size_t)(wrow0 + r) * 512 + k0 + (l & 3) * 8;
      GLDS16(src, buf + ABYTES + c * 16);
    }
  };

  stage(0, 0);
  __syncthreads();
  for (int t = 0; t < 16; t++) {
    if (t < 15) stage((t + 1) * 32, (t + 1) & 1);
    const unsigned char* buf = smem + (t & 1) * BUFB;
    bf16x8 bfr[4][2];
#pragma unroll
    for (int ni = 0; ni < 4; ni++) {
      int r = wn * 64 + ni * 16 + lr;
      const unsigned char* base = buf + ABYTES + r * 128;
      int sw = (r & 7) << 4;
      bfr[ni][0] = *(const bf16x8*)(base + ((lk * 16) ^ sw));
      bfr[ni][1] = *(const bf16x8*)(base + ((64 + lk * 16) ^ sw));
    }
    bf16x8 ah[MFR];
#pragma unroll
    for (int mi = 0; mi < MFR; mi++) {
      int r = wm * (MFR * 16) + mi * 16 + lr;
      ah[mi] = *(const bf16x8*)(buf + r * 64 + ((lk * 16) ^ ((r & 3) << 4)));
    }
#pragma unroll
    for (int mi = 0; mi < MFR; mi++)
#pragma unroll
      for (int ni = 0; ni < 4; ni++) {
        acc[mi][ni] = __builtin_amdgcn_mfma_f32_16x16x32_bf16(ah[mi], bfr[ni][0], acc[mi][ni], 0, 0, 0);
        acc[mi][ni] = __builtin_amdgcn_mfma_f32_16x16x32_bf16(ah[mi], bfr[ni][1], acc[mi][ni], 0, 0, 0);
      }
    __syncthreads();
  }

  const int rowb = row0 + wm * (MFR * 16) + ((lane >> 4) * 4);
  if (MODE == 1) {
#pragma unroll
    for (int mi = 0; mi < MFR; mi++)
#pragma unroll
      for (int ni = 0; ni < 4; ni++) {
        int col = blockIdx.y * 128 + wn * 64 + ni * 16 + (lane & 15);
        float bb = bq[col];
#pragma unroll
        for (int g = 0; g < 4; g++) {
          int rr = rowb + mi * 16 + g;
          oOut[(size_t)rr * 512 + col] = acc[mi][ni][g] + bb;
        }
      }
    return;
  }
  const int region = blockIdx.y >> 2;                 // 0=Q 1=K 2=V
  const float* bias = (region == 0) ? bq : (region == 1) ? bk : bv;
  const int cm0 = (blockIdx.y & 3) * 128;
#pragma unroll
  for (int mi = 0; mi < MFR; mi++)
#pragma unroll
    for (int ni = 0; ni < 4; ni++) {
      int c = cm0 + wn * 64 + ni * 16 + (lane & 15);
      float bb = bias[c];
      if (region == 2) {
#pragma unroll
        for (int g = 0; g < 4; g++) {
          int rr = rowb + mi * 16 + g;
          int b = rr >> 11, s = rr & 2047;
          oVT[((size_t)b * 512 + c) * SP + PAD + s] = (bf16)(acc[mi][ni][g] + bb);
        }
      } else {
        int j = c >> 1, par = c & 1;
#pragma unroll
        for (int g = 0; g < 4; g++) {
          int rr = rowb + mi * 16 + g;
          int s = rr & 2047;
          float v = acc[mi][ni][g] + bb;
          float p = __shfl_xor(v, 1);
          float es = sinT[s * 256 + j], ec = cosT[s * 256 + j];
          float res = par ? (p * es + v * ec) : (v * ec - p * es);
          int oc = par ? (j + 256) : j;
          if (region == 0) oQ[(size_t)rr * 512 + oc] = (bf16)res;
          else { int b = rr >> 11; oK[((size_t)b * SP + PAD + s) * 512 + oc] = (bf16)res; }
        }
      }
    }
}

// ---------------- banded MFMA attention, TQ=16, no duplication ----------
// 256 blocks (B*S/16), 4 waves. Per block: 16 queries, 144 real keys
// (s0..s0+143 padded coords), P padded to 160 key-slots with zeros.
// Phase 1: S[16][144] = Q K^T, 9 key-tiles over 4 waves (wave0 gets 3).
// Phase 2: softmax, 16 lanes/row (valid iff row <= j <= row+127).
// Phase 3: out = P V, 8 chunks of 64 h-rows, 1 out-tile per wave/chunk.
// LDS: [0,2048) Q | [2048,20480) K | [20480,30976) scores f32 [16][164]
//      [30976,36352) P bf16 [16][168] | [36352,56832) V [64][320B]
__global__ __launch_bounds__(256) void attn_mfma_k(
    const bf16* __restrict__ rQb, const bf16* __restrict__ pKb,
    const bf16* __restrict__ pVT, bf16* __restrict__ ab)
{
  __shared__ __align__(16) unsigned char smem[56832];
  const int tid = threadIdx.x, lane = tid & 63, w = tid >> 6;
  const int q0g = blockIdx.x * TQA;
  const int b = q0g >> 11, s0 = q0g & 2047;
  const int lr = lane & 15, lk = lane >> 4;
  const int OFF_K = 2048, OFF_SC = 20480, OFF_P = 30976, OFF_V = 36352;

  // ---- phase 1: scores
  f32x4 sacc[3] = {};
  const int ntile = (w == 0) ? 3 : 2;
  for (int k0 = 0; k0 < 512; k0 += 64) {
    __syncthreads();
    if (tid < 128) {                    // Q: 16 rows x 8 slots (128B/row)
      int r = tid >> 3, p = tid & 7, l = p ^ (r & 7);
      GLDS16(rQb + (size_t)(q0g + r) * 512 + k0 + l * 8, smem + tid * 16);
    }
#pragma unroll
    for (int it = 0; it < 5; it++) {    // K: 144 rows x 8 slots = 1152
      int c = tid + it * 256;
      if (c < 1152) {
        int r = c >> 3, p = c & 7, l = p ^ (r & 7);
        GLDS16(pKb + ((size_t)b * SP + s0 + r) * 512 + k0 + l * 8,
               smem + OFF_K + c * 16);
      }
    }
    __syncthreads();
    __builtin_amdgcn_s_setprio(1);
#pragma unroll
    for (int kk = 0; kk < 2; kk++) {
      bf16x8 a = *(const bf16x8*)(smem + lr * 128 + (((kk * 64 + lk * 16) ^ ((lr & 7) << 4))));
#pragma unroll
      for (int i = 0; i < 3; i++) {
        if (i < ntile) {
          int t = (i < 2) ? (w * 2 + i) : 8;
          int brow = t * 16 + lr;
          bf16x8 bb = *(const bf16x8*)(smem + OFF_K + brow * 128 + (((kk * 64 + lk * 16) ^ ((brow & 7) << 4))));
          sacc[i] = __builtin_amdgcn_mfma_f32_16x16x32_bf16(a, bb, sacc[i], 0, 0, 0);
        }
      }
    }
    __builtin_amdgcn_s_setprio(0);
  }
  __syncthreads();
  {   // write scores f32 [16][164]
    float* sc = (float*)(smem + OFF_SC);
#pragma unroll
    for (int i = 0; i < 3; i++) {
      if (i < ntile) {
        int t = (i < 2) ? (w * 2 + i) : 8;
        int col = t * 16 + lr;
#pragma unroll
        for (int g = 0; g < 4; g++)
          sc[(lk * 4 + g) * 164 + col] = sacc[i][g] * SCALE;
      }
    }
  }
  __syncthreads();
  // ---- phase 2: softmax, 16 threads per row
  {
    float* sc = (float*)(smem + OFF_SC);
    bf16* P = (bf16*)(smem + OFF_P);
    int row = tid >> 4, j0 = tid & 15;
    float vals[9];
    float mx = -1e30f;
#pragma unroll
    for (int i = 0; i < 9; i++) {
      int j = j0 + i * 16;
      bool valid = (j >= row) && (j <= row + 127);
      float v = valid ? sc[row * 164 + j] : -1e30f;
      vals[i] = v;
      mx = fmaxf(mx, v);
    }
#pragma unroll
    for (int off = 1; off < 16; off <<= 1) mx = fmaxf(mx, __shfl_xor(mx, off));
    float sum = 0.f;
#pragma unroll
    for (int i = 0; i < 9; i++) {
      float e = (vals[i] > -1e29f) ? __expf(vals[i] - mx) : 0.f;
      vals[i] = e; sum += e;
    }
#pragma unroll
    for (int off = 1; off < 16; off <<= 1) sum += __shfl_xor(sum, off);
    float inv = 1.f / sum;
#pragma unroll
    for (int i = 0; i < 9; i++)
      P[row * 168 + j0 + i * 16] = (bf16)(vals[i] * inv);   // stride 336B
    P[row * 168 + 144 + j0] = (bf16)0.f;   // zero the 16 pad key-slots
  }
  // ---- phase 3: out = P @ V, 8 chunks of 64 h-rows
  const bf16* pVTb = pVT + (size_t)b * 512 * SP;
  for (int n0 = 0; n0 < 512; n0 += 64) {
    __syncthreads();
#pragma unroll
    for (int it = 0; it < 5; it++) {    // V: 64 rows x 20 slots (320B/row)
      int c = tid + it * 256;
      int r = c / 20, sl = c % 20;
      int keyoff = s0 + sl * 8;
      if (keyoff > SP - 8) keyoff = SP - 8;   // clamp (P=0 there anyway)
      GLDS16(pVTb + (size_t)(n0 + r) * SP + keyoff, smem + OFF_V + c * 16);
    }
    __syncthreads();
    f32x4 oacc = {};
    __builtin_amdgcn_s_setprio(1);
#pragma unroll
    for (int tk = 0; tk < 5; tk++) {
      bf16x8 a = *(const bf16x8*)(smem + OFF_P + lr * 336 + tk * 64 + lk * 16);
      bf16x8 bb = *(const bf16x8*)(smem + OFF_V + (w * 16 + lr) * 320 + tk * 64 + lk * 16);
      oacc = __builtin_amdgcn_mfma_f32_16x16x32_bf16(a, bb, oacc, 0, 0, 0);
    }
    __builtin_amdgcn_s_setprio(0);
    int col = n0 + w * 16 + lr;
#pragma unroll
    for (int g = 0; g < 4; g++)
      ab[(size_t)(q0g + lk * 4 + g) * 512 + col] = (bf16)oacc[g];
  }
}

// ---------------- launch -------------------------------------------------
extern "C" void kernel_launch(void* const* d_in, const int* in_sizes, int n_in,
                              void* d_out, int out_size, void* d_ws, size_t ws_size,
                              hipStream_t stream) {
  const float* x  = (const float*)d_in[0];
  const float* Wq = (const float*)d_in[1];
  const float* bq = (const float*)d_in[2];
  const float* Wk = (const float*)d_in[3];
  const float* bk = (const float*)d_in[4];
  const float* Wv = (const float*)d_in[5];
  const float* bv = (const float*)d_in[6];
  const float* Wo = (const float*)d_in[7];
  const float* bo = (const float*)d_in[8];
  float* out = (float*)d_out;

  const size_t NQ = (size_t)B_SZ * S_LEN * H_DIM;  // 2,097,152
  const size_t NP = (size_t)B_SZ * SP * H_DIM;     // 2,228,224
  float* sinT = (float*)d_ws;                      // 524288 f32
  float* cosT = sinT + (size_t)S_LEN * 256;        // 524288 f32
  bf16* xb  = (bf16*)(cosT + (size_t)S_LEN * 256); // NQ
  bf16* whi = xb + NQ;                             // 1M
  bf16* wlo = whi + 2048 * 512;                    // 1M
  bf16* rQb = wlo + 2048 * 512;                    // NQ
  bf16* pKb = rQb + NQ;                            // NP
  bf16* pVT = pKb + NP;                            // NP
  bf16* ab  = pVT + NP;                            // NQ

  prep_k<<<3200, 256, 0, stream>>>(x, Wq, Wk, Wv, Wo, xb, whi, wlo,
                                   pKb, pVT, sinT, cosT);

  gemm_k<4, 0><<<dim3(32, 12), 256, 0, stream>>>(xb, whi, wlo,
      bq, bk, bv, sinT, cosT, rQb, pKb, pVT, nullptr);

  attn_mfma_k<<<B_SZ * S_LEN / TQA, 256, 0, stream>>>(rQb, pKb, pVT, ab);

  gemm_k<2, 1><<<dim3(64, 4), 256, 0, stream>>>(ab, whi, wlo,
      bo, nullptr, nullptr, sinT, cosT, nullptr, nullptr, nullptr, out);
}

// Round 10
// 48.647 us; speedup vs baseline: 1.5904x; 1.2657x over previous
//
#include <hip/hip_runtime.h>
#include <math.h>

#define S_LEN 2048
#define B_SZ  2
#define H_DIM 512
#define WIN   128
#define PAD   64
#define SP    (S_LEN + WIN)   /* 2176 padded seq length */
#define SCALE 0.044194173824159216f  /* 1/sqrt(512) */
#define TQ    32

typedef __bf16 bf16;
typedef __attribute__((ext_vector_type(8))) __bf16 bf16x8;
typedef __attribute__((ext_vector_type(4))) __bf16 bf16x4;
typedef __attribute__((ext_vector_type(4))) float f32x4;

#define GLDS16(g, l) __builtin_amdgcn_global_load_lds( \
    (const __attribute__((address_space(1))) void*)(g), \
    (__attribute__((address_space(3))) void*)(l), 16, 0, 0)

// ---------------- fused prep: x->bf16 | W->bf16 | pads | rope tables ----
// R0: [0,262144)       x -> xb (8 elems/thread)
// R1: [262144,524288)  Wq|Wk|Wv|Wo -> wb bf16 concat [2048][512] (4/thread)
// R2: [524288,557056)  zero pads of pKb (row-pad) and pVT (col-pad)
// R3: [557056,819200)  rope tables via exp2f/sinf (f32)
__global__ __launch_bounds__(256) void prep_k(
    const float* __restrict__ x,
    const float* __restrict__ Wq, const float* __restrict__ Wk,
    const float* __restrict__ Wv, const float* __restrict__ Wo,
    bf16* __restrict__ xb, bf16* __restrict__ wb,
    bf16* __restrict__ pKb, bf16* __restrict__ pVT,
    float* __restrict__ sinT, float* __restrict__ cosT)
{
  int i = blockIdx.x * 256 + threadIdx.x;
  if (i < 262144) {                     // R0: x -> bf16
    int e = i * 8;
    float4 v0 = *(const float4*)(x + e);
    float4 v1 = *(const float4*)(x + e + 4);
    bf16x8 o = {(bf16)v0.x, (bf16)v0.y, (bf16)v0.z, (bf16)v0.w,
                (bf16)v1.x, (bf16)v1.y, (bf16)v1.z, (bf16)v1.w};
    *(bf16x8*)(xb + e) = o;
  } else if (i < 524288) {              // R1: weights -> bf16 (1-pass)
    int idx = (i - 262144) * 4;
    int m = idx >> 18;
    const float* src = (m == 0) ? Wq : (m == 1) ? Wk : (m == 2) ? Wv : Wo;
    float4 v = *(const float4*)(src + (idx & 262143));
    bf16x4 hv = {(bf16)v.x, (bf16)v.y, (bf16)v.z, (bf16)v.w};
    *(bf16x4*)(wb + idx) = hv;
  } else if (i < 557056) {              // R2: pads
    int idx = i - 524288;
    float4 z = {0.f, 0.f, 0.f, 0.f};
    if (idx < 16384) {        // pKb: 2b x 128 pad-rows x 512 cols
      int b = idx >> 13, r = (idx & 8191) >> 6, c = idx & 63;
      int row = (r < 64) ? r : (S_LEN + r);
      *(float4*)(pKb + ((size_t)b * SP + row) * 512 + c * 8) = z;
    } else {                  // pVT: 2b x 512 rows x 128 pad-cols
      int j = idx - 16384;
      int b = j >> 13, h = (j & 8191) >> 4, v = j & 15;
      int col = (v < 8) ? v * 8 : (S_LEN + PAD + (v - 8) * 8);
      *(float4*)(pVT + ((size_t)b * 512 + h) * SP + col) = z;
    }
  } else {                              // R3: rope tables
    int idx = i - 557056;               // [0, 262144) = s*128 + jj
    int s = idx >> 7, jj = idx & 127;
    float fqA = exp2f(-(float)jj * 0.10381025296523f);          // i = 2jj
    float fqB = exp2f(-(float)(2 * jj + 1) * 0.05190512648262f); // i = 2jj+1
    float aA = (float)s * fqA;
    float aB = (float)s * fqB;
    sinT[s * 256 + jj]       = sinf(aA);
    sinT[s * 256 + jj + 128] = cosf(aA);
    cosT[s * 256 + jj]       = sinf(aB);
    cosT[s * 256 + jj + 128] = cosf(aB);
  }
}

// ---------------- 1-pass bf16 MFMA GEMM, BK=64 --------------------------
// C = A(bf16) @ Wb(bf16)^T (+bias/rope epilogue).
// MODE 0: fused QKV -> bf16 rQ (rope), bf16 pK (rope+pad), bf16 pVT (T+pad)
// MODE 1: O-proj -> f32 out (bias in bq slot)
// LDS rows 128B (64 bf16 = full BK), XOR (r&7)<<4; gload_lds linear dest +
// inverse-swizzled global source (rule 21). Double-buffered.
template<int MFR, int MODE>
__global__ __launch_bounds__(256) void gemm_k(
    const bf16* __restrict__ Ab, const bf16* __restrict__ Wb,
    const float* __restrict__ bq, const float* __restrict__ bk,
    const float* __restrict__ bv,
    const float* __restrict__ sinT, const float* __restrict__ cosT,
    bf16* __restrict__ oQ, bf16* __restrict__ oK, bf16* __restrict__ oVT,
    float* __restrict__ oOut)
{
  constexpr int BM = MFR * 32;
  constexpr int ABYTES = BM * 128;
  constexpr int BUFB = ABYTES + 128 * 128;
  __shared__ __align__(16) unsigned char smem[2 * BUFB];
  const int tid = threadIdx.x;
  const int lane = tid & 63, wid = tid >> 6;
  const int wm = wid >> 1, wn = wid & 1;
  const int row0 = blockIdx.x * BM;
  const int wrow0 = (MODE == 0 ? 0 : 1536) + blockIdx.y * 128;
  const int lr = lane & 15, lk = lane >> 4;

  f32x4 acc[MFR][4] = {};

  auto stage = [&](int k0, int bufsel) {
    unsigned char* buf = smem + bufsel * BUFB;
#pragma unroll
    for (int i = 0; i < MFR; i++) {         // A: BM rows x 8 slots of 16B
      int c = tid + i * 256;
      int r = c >> 3, p = c & 7, l = p ^ (r & 7);
      GLDS16(Ab + (size_t)(row0 + r) * 512 + k0 + l * 8, buf + c * 16);
    }
#pragma unroll
    for (int j = 0; j < 4; j++) {           // B: 128 rows x 8 slots of 16B
      int c = tid + j * 256;
      int r = c >> 3, p = c & 7, l = p ^ (r & 7);
      GLDS16(Wb + (size_t)(wrow0 + r) * 512 + k0 + l * 8, buf + ABYTES + c * 16);
    }
  };

  stage(0, 0);
  __syncthreads();
  for (int t = 0; t < 8; t++) {
    if (t < 7) stage((t + 1) * 64, (t + 1) & 1);
    const unsigned char* buf = smem + (t & 1) * BUFB;
    bf16x8 bfr[4][2];
#pragma unroll
    for (int ni = 0; ni < 4; ni++) {
      int r = wn * 64 + ni * 16 + lr;
      const unsigned char* base = buf + ABYTES + r * 128;
      int sw = (r & 7) << 4;
      bfr[ni][0] = *(const bf16x8*)(base + ((lk * 16) ^ sw));
      bfr[ni][1] = *(const bf16x8*)(base + ((64 + lk * 16) ^ sw));
    }
#pragma unroll
    for (int mi = 0; mi < MFR; mi++) {
      int r = wm * (MFR * 16) + mi * 16 + lr;
      const unsigned char* base = buf + r * 128;
      int sw = (r & 7) << 4;
      bf16x8 a0 = *(const bf16x8*)(base + ((lk * 16) ^ sw));
      bf16x8 a1 = *(const bf16x8*)(base + ((64 + lk * 16) ^ sw));
#pragma unroll
      for (int ni = 0; ni < 4; ni++) {
        acc[mi][ni] = __builtin_amdgcn_mfma_f32_16x16x32_bf16(a0, bfr[ni][0], acc[mi][ni], 0, 0, 0);
        acc[mi][ni] = __builtin_amdgcn_mfma_f32_16x16x32_bf16(a1, bfr[ni][1], acc[mi][ni], 0, 0, 0);
      }
    }
    __syncthreads();
  }

  const int rowb = row0 + wm * (MFR * 16) + ((lane >> 4) * 4);
  if (MODE == 1) {
#pragma unroll
    for (int mi = 0; mi < MFR; mi++)
#pragma unroll
      for (int ni = 0; ni < 4; ni++) {
        int col = blockIdx.y * 128 + wn * 64 + ni * 16 + (lane & 15);
        float bb = bq[col];
#pragma unroll
        for (int g = 0; g < 4; g++) {
          int rr = rowb + mi * 16 + g;
          oOut[(size_t)rr * 512 + col] = acc[mi][ni][g] + bb;
        }
      }
    return;
  }
  const int region = blockIdx.y >> 2;                 // 0=Q 1=K 2=V
  const float* bias = (region == 0) ? bq : (region == 1) ? bk : bv;
  const int cm0 = (blockIdx.y & 3) * 128;
#pragma unroll
  for (int mi = 0; mi < MFR; mi++)
#pragma unroll
    for (int ni = 0; ni < 4; ni++) {
      int c = cm0 + wn * 64 + ni * 16 + (lane & 15);
      float bb = bias[c];
      if (region == 2) {
#pragma unroll
        for (int g = 0; g < 4; g++) {
          int rr = rowb + mi * 16 + g;
          int b = rr >> 11, s = rr & 2047;
          oVT[((size_t)b * 512 + c) * SP + PAD + s] = (bf16)(acc[mi][ni][g] + bb);
        }
      } else {
        int j = c >> 1, par = c & 1;
#pragma unroll
        for (int g = 0; g < 4; g++) {
          int rr = rowb + mi * 16 + g;
          int s = rr & 2047;
          float v = acc[mi][ni][g] + bb;
          float p = __shfl_xor(v, 1);
          float es = sinT[s * 256 + j], ec = cosT[s * 256 + j];
          float res = par ? (p * es + v * ec) : (v * ec - p * es);
          int oc = par ? (j + 256) : j;
          if (region == 0) oQ[(size_t)rr * 512 + oc] = (bf16)res;
          else { int b = rr >> 11; oK[((size_t)b * SP + PAD + s) * 512 + oc] = (bf16)res; }
        }
      }
    }
}

// ---------------- banded MFMA attention (round-7 verified) --------------
// grid (128, 2): block = 32 queries x 256 output h-cols (y half).
__global__ __launch_bounds__(256) void attn_mfma_k(
    const bf16* __restrict__ rQb, const bf16* __restrict__ pKb,
    const bf16* __restrict__ pVT, bf16* __restrict__ ab)
{
  __shared__ __align__(16) unsigned char smem[53760];
  const int tid = threadIdx.x, lane = tid & 63, w = tid >> 6;
  const int q0g = blockIdx.x * TQ;
  const int nbase = blockIdx.y * 256;
  const int b = q0g >> 11, s0 = q0g & 2047;
  const int lr = lane & 15, lk = lane >> 4;
  const int OFF_K = 4096, OFF_P = 43008;

  // ---- phase 1: scores
  f32x4 sacc[5] = {};
  const int tm = w >> 1, tnb = (w & 1) * 5;
  for (int k0 = 0; k0 < 512; k0 += 64) {
    __syncthreads();
    {
      int r = tid >> 3, p = tid & 7, l = p ^ (r & 7);
      GLDS16(rQb + (size_t)(q0g + r) * 512 + k0 + l * 8, smem + (w * 64) * 16);
    }
#pragma unroll
    for (int i = 0; i < 5; i++) {
      int c = tid + i * 256;
      int r = c >> 3, p = c & 7, l = p ^ (r & 7);
      GLDS16(pKb + ((size_t)b * SP + s0 + r) * 512 + k0 + l * 8,
             smem + OFF_K + (i * 256 + w * 64) * 16);
    }
    __syncthreads();
    __builtin_amdgcn_s_setprio(1);
#pragma unroll
    for (int kk = 0; kk < 2; kk++) {
      int arow = tm * 16 + lr;
      bf16x8 a = *(const bf16x8*)(smem + arow * 128 + (((kk * 64 + lk * 16) ^ ((arow & 7) << 4))));
#pragma unroll
      for (int i = 0; i < 5; i++) {
        int brow = (tnb + i) * 16 + lr;
        bf16x8 bb = *(const bf16x8*)(smem + OFF_K + brow * 128 + (((kk * 64 + lk * 16) ^ ((brow & 7) << 4))));
        sacc[i] = __builtin_amdgcn_mfma_f32_16x16x32_bf16(a, bb, sacc[i], 0, 0, 0);
      }
    }
    __builtin_amdgcn_s_setprio(0);
  }
  __syncthreads();
  {   // write scores f32 [32][164]
    float* sc = (float*)smem;
#pragma unroll
    for (int i = 0; i < 5; i++) {
      int col = (tnb + i) * 16 + lr;
#pragma unroll
      for (int g = 0; g < 4; g++) {
        int row = tm * 16 + lk * 4 + g;
        sc[row * 164 + col] = sacc[i][g] * SCALE;
      }
    }
  }
  __syncthreads();
  // ---- phase 2: banded softmax, 8 threads per row
  {
    float* sc = (float*)smem;
    bf16* P = (bf16*)(smem + OFF_P);
    int row = tid >> 3, j0 = tid & 7;
    float vals[20];
    float mx = -1e30f;
#pragma unroll
    for (int i = 0; i < 20; i++) {
      int j = j0 + i * 8;
      bool valid = (j >= row) && (j <= row + 127);
      float v = valid ? sc[row * 164 + j] : -1e30f;
      vals[i] = v;
      mx = fmaxf(mx, v);
    }
#pragma unroll
    for (int off = 1; off < 8; off <<= 1) mx = fmaxf(mx, __shfl_xor(mx, off));
    float sum = 0.f;
#pragma unroll
    for (int i = 0; i < 20; i++) {
      float e = (vals[i] > -1e29f) ? __expf(vals[i] - mx) : 0.f;
      vals[i] = e; sum += e;
    }
#pragma unroll
    for (int off = 1; off < 8; off <<= 1) sum += __shfl_xor(sum, off);
    float inv = 1.f / sum;
#pragma unroll
    for (int i = 0; i < 20; i++) {
      int j = j0 + i * 8;
      P[row * 168 + j] = (bf16)(vals[i] * inv);   // row stride 336B
    }
  }
  // ---- phase 3: out = P @ V (this block's 256-col half)
  const bf16* pVTb = pVT + (size_t)b * 512 * SP;
  const int utm = w >> 1, utnb = (w & 1) * 4;
  for (int n0 = nbase; n0 < nbase + 256; n0 += 128) {
    __syncthreads();
    {   // stage V chunk: 128 h-rows x 160 keys, LDS row stride 336B
      int r = tid >> 1, half = tid & 1;
      const bf16* src = pVTb + (size_t)(n0 + r) * SP + s0;
#pragma unroll
      for (int i = 0; i < 10; i++) {
        int slot = half * 10 + i;
        float4 v = *(const float4*)(src + slot * 8);
        *(float4*)(smem + r * 336 + slot * 16) = v;
      }
    }
    __syncthreads();
    f32x4 oacc[4] = {};
    __builtin_amdgcn_s_setprio(1);
#pragma unroll
    for (int tk = 0; tk < 5; tk++) {
      int arow = utm * 16 + lr;
      bf16x8 a = *(const bf16x8*)(smem + OFF_P + arow * 336 + tk * 64 + lk * 16);
#pragma unroll
      for (int i = 0; i < 4; i++) {
        int brow = (utnb + i) * 16 + lr;
        bf16x8 bb = *(const bf16x8*)(smem + brow * 336 + tk * 64 + lk * 16);
        oacc[i] = __builtin_amdgcn_mfma_f32_16x16x32_bf16(a, bb, oacc[i], 0, 0, 0);
      }
    }
    __builtin_amdgcn_s_setprio(0);
#pragma unroll
    for (int i = 0; i < 4; i++) {
      int col = n0 + (utnb + i) * 16 + lr;
#pragma unroll
      for (int g = 0; g < 4; g++) {
        int row = utm * 16 + lk * 4 + g;
        ab[(size_t)(q0g + row) * 512 + col] = (bf16)oacc[i][g];
      }
    }
  }
}

// ---------------- launch -------------------------------------------------
extern "C" void kernel_launch(void* const* d_in, const int* in_sizes, int n_in,
                              void* d_out, int out_size, void* d_ws, size_t ws_size,
                              hipStream_t stream) {
  const float* x  = (const float*)d_in[0];
  const float* Wq = (const float*)d_in[1];
  const float* bq = (const float*)d_in[2];
  const float* Wk = (const float*)d_in[3];
  const float* bk = (const float*)d_in[4];
  const float* Wv = (const float*)d_in[5];
  const float* bv = (const float*)d_in[6];
  const float* Wo = (const float*)d_in[7];
  const float* bo = (const float*)d_in[8];
  float* out = (float*)d_out;

  const size_t NQ = (size_t)B_SZ * S_LEN * H_DIM;  // 2,097,152
  const size_t NP = (size_t)B_SZ * SP * H_DIM;     // 2,228,224
  float* sinT = (float*)d_ws;                      // 524288 f32
  float* cosT = sinT + (size_t)S_LEN * 256;        // 524288 f32
  bf16* xb  = (bf16*)(cosT + (size_t)S_LEN * 256); // NQ
  bf16* wb  = xb + NQ;                             // 2048*512
  bf16* rQb = wb + 2048 * 512;                     // NQ
  bf16* pKb = rQb + NQ;                            // NP
  bf16* pVT = pKb + NP;                            // NP
  bf16* ab  = pVT + NP;                            // NQ

  prep_k<<<3200, 256, 0, stream>>>(x, Wq, Wk, Wv, Wo, xb, wb,
                                   pKb, pVT, sinT, cosT);

  gemm_k<4, 0><<<dim3(32, 12), 256, 0, stream>>>(xb, wb,
      bq, bk, bv, sinT, cosT, rQb, pKb, pVT, nullptr);

  attn_mfma_k<<<dim3(B_SZ * S_LEN / TQ, 2), 256, 0, stream>>>(rQb, pKb, pVT, ab);

  gemm_k<2, 1><<<dim3(64, 4), 256, 0, stream>>>(ab, wb,
      bo, nullptr, nullptr, sinT, cosT, nullptr, nullptr, nullptr, out);
}